// Round 3
// baseline (532.769 us; speedup 1.0000x reference)
//
#include <hip/hip_runtime.h>

#define N_NODES 50000
#define N_EDGES 1600000
#define D_FEAT 32
#define SCAN_BLOCK 1024
#define N_SCAN_BLOCKS ((N_NODES + SCAN_BLOCK - 1) / SCAN_BLOCK)  // 49

// ws layout (int units):
//   cnt   [0, N)          per-dst edge count (histogram)
//   excl  [N, 2N)         per-block exclusive scan of cnt
//   om    [2N, 3N)        mutable offset cursors (scatter claims slots here)
//   bsum  [3N, 3N+64)
//   bsumx [3N+64, 3N+128)
//   eid   [3N+128, 3N+128+E)   edge ids sorted by dst (6.4 MB)
#define WS_CNT   0
#define WS_EXCL  (N_NODES)
#define WS_OM    (2 * N_NODES)
#define WS_BSUM  (3 * N_NODES)
#define WS_BSUMX (3 * N_NODES + 64)
#define WS_EID   (3 * N_NODES + 128)

typedef float f4 __attribute__((ext_vector_type(4)));

// -------- main path --------

// histogram of dst, int4-vectorized (E divisible by 4)
__global__ void hist(const int* __restrict__ dst, int* __restrict__ cnt) {
    int q = blockIdx.x * blockDim.x + threadIdx.x;
    const int NQ = N_EDGES / 4;
    if (q >= NQ) return;
    int4 d4 = ((const int4*)dst)[q];
    atomicAdd(&cnt[d4.x], 1);
    atomicAdd(&cnt[d4.y], 1);
    atomicAdd(&cnt[d4.z], 1);
    atomicAdd(&cnt[d4.w], 1);
}

__global__ void scan_blocks(const int* __restrict__ cnt,
                            int* __restrict__ excl,
                            int* __restrict__ bsum) {
    __shared__ int lds[SCAN_BLOCK];
    int tid = threadIdx.x;
    int i = blockIdx.x * SCAN_BLOCK + tid;
    int v = (i < N_NODES) ? cnt[i] : 0;
    int sum = v;
    lds[tid] = v;
    __syncthreads();
    for (int ofs = 1; ofs < SCAN_BLOCK; ofs <<= 1) {
        int t = (tid >= ofs) ? lds[tid - ofs] : 0;
        __syncthreads();
        sum += t;
        lds[tid] = sum;
        __syncthreads();
    }
    if (i < N_NODES) excl[i] = sum - v;
    if (tid == SCAN_BLOCK - 1) bsum[blockIdx.x] = lds[SCAN_BLOCK - 1];
}

// one wave: shuffle-based exclusive scan of the 49 block sums
__global__ void scan_bsums(const int* __restrict__ bsum, int* __restrict__ bsumx) {
    int lane = threadIdx.x;
    int orig = (lane < N_SCAN_BLOCKS) ? bsum[lane] : 0;
    int v = orig;
    for (int o = 1; o < 64; o <<= 1) {
        int t = __shfl_up(v, o);
        if (lane >= o) v += t;
    }
    if (lane < N_SCAN_BLOCKS) bsumx[lane] = v - orig;
}

// om[i] = global exclusive offset (mutable cursor consumed by scatter)
__global__ void finalize_off(const int* __restrict__ excl,
                             const int* __restrict__ bsumx,
                             int* __restrict__ om) {
    int i = blockIdx.x * SCAN_BLOCK + threadIdx.x;
    if (i < N_NODES) om[i] = excl[i] + bsumx[blockIdx.x];
}

// Claim dst-sorted slots via atomic cursor; write only the 4B edge id.
// 4B records halve the dirty-sector count vs 8B pairs (less cross-XCD
// partial-line write amplification); rank round-trip eliminated.
__global__ void scatter_eid(const int* __restrict__ dst,
                            int* __restrict__ om,
                            int* __restrict__ eid) {
    int q = blockIdx.x * blockDim.x + threadIdx.x;
    const int NQ = N_EDGES / 4;
    if (q >= NQ) return;
    int4 d4 = ((const int4*)dst)[q];
    int e0 = q * 4;
    eid[atomicAdd(&om[d4.x], 1)] = e0;
    eid[atomicAdd(&om[d4.y], 1)] = e0 + 1;
    eid[atomicAdd(&om[d4.z], 1)] = e0 + 2;
    eid[atomicAdd(&om[d4.w], 1)] = e0 + 3;
}

// per (node, float4-group): walk the node's contiguous eid records, gather
// edge_feat/node_feat rows, relu-sum on the fly, add eps-scaled residual.
// Lane g loads its own edge id + that edge's src up front (coalesced / L2),
// then both are shfl-broadcast across the 8-lane group (R1 structure).
__global__ void reduce_gather(const float* __restrict__ node_feat,
                              const float* __restrict__ edge_feat,
                              const float* __restrict__ eps,
                              const int* __restrict__ src,
                              const int* __restrict__ excl,
                              const int* __restrict__ bsumx,
                              const int* __restrict__ cnt,
                              const int* __restrict__ eid,
                              float* __restrict__ out) {
    int t = blockIdx.x * blockDim.x + threadIdx.x;
    int n = t >> 3;
    int g = t & 7;
    if (n >= N_NODES) return;

    int start = excl[n] + bsumx[n >> 10];
    int c = cnt[n];
    int gbase = (threadIdx.x & 63) & ~7;  // base lane of this 8-lane group

    const f4* efp = (const f4*)edge_feat;
    const f4* nfp = (const f4*)node_feat;

    f4 acc = (f4)(0.f);
    int i0 = 0;
    for (; i0 + 8 <= c; i0 += 8) {
        int p  = eid[start + i0 + g];  // 8 lanes x 4B = 32B coalesced
        int sv = src[p];               // own edge's src (random 4B, L2-resident)
#pragma unroll
        for (int j = 0; j < 8; ++j) {
            int e = __shfl(p,  gbase + j);
            int s = __shfl(sv, gbase + j);
            f4 ef = __builtin_nontemporal_load(&efp[(size_t)e * 8 + g]);
            f4 nf = nfp[(size_t)s * 8 + g];
            acc.x += fmaxf(nf.x + ef.x, 0.f);
            acc.y += fmaxf(nf.y + ef.y, 0.f);
            acc.z += fmaxf(nf.z + ef.z, 0.f);
            acc.w += fmaxf(nf.w + ef.w, 0.f);
        }
    }
    int rem = c - i0;
    if (rem > 0) {
        int p  = (g < rem) ? eid[start + i0 + g] : 0;
        int sv = src[p];
        for (int j = 0; j < rem; ++j) {
            int e = __shfl(p,  gbase + j);
            int s = __shfl(sv, gbase + j);
            f4 ef = __builtin_nontemporal_load(&efp[(size_t)e * 8 + g]);
            f4 nf = nfp[(size_t)s * 8 + g];
            acc.x += fmaxf(nf.x + ef.x, 0.f);
            acc.y += fmaxf(nf.y + ef.y, 0.f);
            acc.z += fmaxf(nf.z + ef.z, 0.f);
            acc.w += fmaxf(nf.w + ef.w, 0.f);
        }
    }

    float scale = 1.0f + eps[0];
    f4 h = nfp[(size_t)n * 8 + g];
    f4 o;
    o.x = scale * h.x + acc.x;
    o.y = scale * h.y + acc.y;
    o.z = scale * h.z + acc.z;
    o.w = scale * h.w + acc.w;
    ((f4*)out)[(size_t)n * 8 + g] = o;
}

// -------- fallback path (tiny ws): direct atomics --------

__global__ void fb_init_out(const float* __restrict__ node_feat,
                            const float* __restrict__ eps,
                            float* __restrict__ out) {
    int i = blockIdx.x * blockDim.x + threadIdx.x;
    const int n4 = N_NODES * D_FEAT / 4;
    float scale = 1.0f + eps[0];
    if (i < n4) {
        float4 v = ((const float4*)node_feat)[i];
        v.x *= scale; v.y *= scale; v.z *= scale; v.w *= scale;
        ((float4*)out)[i] = v;
    }
}

__global__ void fb_scatter(const float* __restrict__ node_feat,
                           const float* __restrict__ edge_feat,
                           const int* __restrict__ src,
                           const int* __restrict__ dst,
                           float* __restrict__ out) {
    int t = blockIdx.x * blockDim.x + threadIdx.x;
    int e = t >> 3;
    int g = t & 7;
    if (e >= N_EDGES) return;
    int s = src[e];
    int d = dst[e];
    float4 nf = ((const float4*)node_feat)[s * 8 + g];
    float4 ef = ((const float4*)edge_feat)[(size_t)e * 8 + g];
    float* op = out + (size_t)d * D_FEAT + g * 4;
    unsafeAtomicAdd(op + 0, fmaxf(nf.x + ef.x, 0.f));
    unsafeAtomicAdd(op + 1, fmaxf(nf.y + ef.y, 0.f));
    unsafeAtomicAdd(op + 2, fmaxf(nf.z + ef.z, 0.f));
    unsafeAtomicAdd(op + 3, fmaxf(nf.w + ef.w, 0.f));
}

extern "C" void kernel_launch(void* const* d_in, const int* in_sizes, int n_in,
                              void* d_out, int out_size, void* d_ws, size_t ws_size,
                              hipStream_t stream) {
    const float* node_feat = (const float*)d_in[0];
    const float* edge_feat = (const float*)d_in[1];
    const float* eps       = (const float*)d_in[2];
    const int*   src       = (const int*)d_in[3];
    const int*   dst       = (const int*)d_in[4];
    float* out = (float*)d_out;

    const int B = 256;
    const size_t need = ((size_t)WS_EID + (size_t)N_EDGES) * sizeof(int);

    if (ws_size < need) {
        // fallback: direct fp32 atomics (no ws)
        int n4 = N_NODES * D_FEAT / 4;
        fb_init_out<<<(n4 + B - 1) / B, B, 0, stream>>>(node_feat, eps, out);
        long long total = (long long)N_EDGES * 8;
        fb_scatter<<<(int)((total + B - 1) / B), B, 0, stream>>>(
            node_feat, edge_feat, src, dst, out);
        return;
    }

    int* ws = (int*)d_ws;
    int*  cnt   = ws + WS_CNT;
    int*  excl  = ws + WS_EXCL;
    int*  om    = ws + WS_OM;
    int*  bsum  = ws + WS_BSUM;
    int*  bsumx = ws + WS_BSUMX;
    int*  eid   = ws + WS_EID;

    hipMemsetAsync(cnt, 0, N_NODES * sizeof(int), stream);

    int nq = N_EDGES / 4;
    hist<<<(nq + B - 1) / B, B, 0, stream>>>(dst, cnt);
    scan_blocks<<<N_SCAN_BLOCKS, SCAN_BLOCK, 0, stream>>>(cnt, excl, bsum);
    scan_bsums<<<1, 64, 0, stream>>>(bsum, bsumx);
    finalize_off<<<N_SCAN_BLOCKS, SCAN_BLOCK, 0, stream>>>(excl, bsumx, om);

    scatter_eid<<<(nq + B - 1) / B, B, 0, stream>>>(dst, om, eid);

    long long ntotal = (long long)N_NODES * 8;
    reduce_gather<<<(int)((ntotal + B - 1) / B), B, 0, stream>>>(
        node_feat, edge_feat, eps, src, excl, bsumx, cnt, eid, out);
}

// Round 4
// 426.826 us; speedup vs baseline: 1.2482x; 1.2482x over previous
//
#include <hip/hip_runtime.h>

#define N_NODES 50000
#define N_EDGES 1600000
#define D_FEAT 32
#define SCAN_BLOCK 1024
#define N_SCAN_BLOCKS ((N_NODES + SCAN_BLOCK - 1) / SCAN_BLOCK)  // 49

// ws layout (int units):
//   cnt   [0, N)          per-dst edge count (histogram)
//   excl  [N, 2N)         per-block exclusive scan of cnt
//   bsum  [2N, 2N+64)
//   bsumx [2N+64, 2N+128)
//   rank  [2N+128, 2N+128+E)       rank of edge within its dst bin
//   pair  [2N+128+E, 2N+128+3E)    int2 {e, src[e]} sorted by dst (12.8 MB)
#define WS_CNT   0
#define WS_EXCL  (N_NODES)
#define WS_BSUM  (2 * N_NODES)
#define WS_BSUMX (2 * N_NODES + 64)
#define WS_RANK  (2 * N_NODES + 128)
#define WS_PAIR  (2 * N_NODES + 128 + N_EDGES)

typedef float f4 __attribute__((ext_vector_type(4)));

// -------- main path --------

// rank[e] = old count of dst[e]; cnt accumulates histogram.
// int4-vectorized: 4 edges/thread, 4 independent atomics, coalesced int4 rank store.
__global__ void hist_rank(const int* __restrict__ dst,
                          int* __restrict__ cnt,
                          int* __restrict__ rank) {
    int q = blockIdx.x * blockDim.x + threadIdx.x;
    const int NQ = N_EDGES / 4;
    if (q >= NQ) return;
    int4 d4 = ((const int4*)dst)[q];
    int4 r4;
    r4.x = atomicAdd(&cnt[d4.x], 1);
    r4.y = atomicAdd(&cnt[d4.y], 1);
    r4.z = atomicAdd(&cnt[d4.z], 1);
    r4.w = atomicAdd(&cnt[d4.w], 1);
    ((int4*)rank)[q] = r4;
}

__global__ void scan_blocks(const int* __restrict__ cnt,
                            int* __restrict__ excl,
                            int* __restrict__ bsum) {
    __shared__ int lds[SCAN_BLOCK];
    int tid = threadIdx.x;
    int i = blockIdx.x * SCAN_BLOCK + tid;
    int v = (i < N_NODES) ? cnt[i] : 0;
    int sum = v;
    lds[tid] = v;
    __syncthreads();
    for (int ofs = 1; ofs < SCAN_BLOCK; ofs <<= 1) {
        int t = (tid >= ofs) ? lds[tid - ofs] : 0;
        __syncthreads();
        sum += t;
        lds[tid] = sum;
        __syncthreads();
    }
    if (i < N_NODES) excl[i] = sum - v;
    if (tid == SCAN_BLOCK - 1) bsum[blockIdx.x] = lds[SCAN_BLOCK - 1];
}

// one wave: shuffle-based exclusive scan of the 49 block sums
__global__ void scan_bsums(const int* __restrict__ bsum, int* __restrict__ bsumx) {
    int lane = threadIdx.x;
    int orig = (lane < N_SCAN_BLOCKS) ? bsum[lane] : 0;
    int v = orig;
    for (int o = 1; o < 64; o <<= 1) {
        int t = __shfl_up(v, o);
        if (lane >= o) v += t;
    }
    if (lane < N_SCAN_BLOCKS) bsumx[lane] = v - orig;
}

// Scatter 8-byte records {e, src[e]} to dst-sorted positions (rank-based, no
// atomics in the store path -> fire-and-forget stores at full rate).
// off[d] computed inline as excl[d] + bsumx[d>>10]. 4 edges/thread, int4 reads.
__global__ void scatter_pairs(const int* __restrict__ src,
                              const int* __restrict__ dst,
                              const int* __restrict__ excl,
                              const int* __restrict__ bsumx,
                              const int* __restrict__ rank,
                              int2* __restrict__ pair) {
    int q = blockIdx.x * blockDim.x + threadIdx.x;
    const int NQ = N_EDGES / 4;
    if (q >= NQ) return;
    int4 d4 = ((const int4*)dst)[q];
    int4 s4 = ((const int4*)src)[q];
    int4 r4 = ((const int4*)rank)[q];
    int e0 = q * 4;
    pair[excl[d4.x] + bsumx[d4.x >> 10] + r4.x] = make_int2(e0,     s4.x);
    pair[excl[d4.y] + bsumx[d4.y >> 10] + r4.y] = make_int2(e0 + 1, s4.y);
    pair[excl[d4.z] + bsumx[d4.z >> 10] + r4.z] = make_int2(e0 + 2, s4.z);
    pair[excl[d4.w] + bsumx[d4.w >> 10] + r4.w] = make_int2(e0 + 3, s4.w);
}

// per (node, float4-group): walk the node's contiguous pair records, gather
// edge_feat/node_feat rows, relu-sum on the fly, add eps-scaled residual.
// 8-lane groups broadcast pair records via shfl; main loop fully unrolled.
__global__ void reduce_gather(const float* __restrict__ node_feat,
                              const float* __restrict__ edge_feat,
                              const float* __restrict__ eps,
                              const int* __restrict__ excl,
                              const int* __restrict__ bsumx,
                              const int* __restrict__ cnt,
                              const int2* __restrict__ pair,
                              float* __restrict__ out) {
    int t = blockIdx.x * blockDim.x + threadIdx.x;
    int n = t >> 3;
    int g = t & 7;
    if (n >= N_NODES) return;

    int start = excl[n] + bsumx[n >> 10];
    int c = cnt[n];
    int gbase = (threadIdx.x & 63) & ~7;  // base lane of this 8-lane group

    const f4* efp = (const f4*)edge_feat;
    const f4* nfp = (const f4*)node_feat;

    f4 acc = (f4)(0.f);
    int i0 = 0;
    for (; i0 + 8 <= c; i0 += 8) {
        int2 p = pair[start + i0 + g];  // 8 lanes x 8B = 64B coalesced
#pragma unroll
        for (int j = 0; j < 8; ++j) {
            int e = __shfl(p.x, gbase + j);
            int s = __shfl(p.y, gbase + j);
            f4 ef = __builtin_nontemporal_load(&efp[(size_t)e * 8 + g]);
            f4 nf = nfp[(size_t)s * 8 + g];
            acc.x += fmaxf(nf.x + ef.x, 0.f);
            acc.y += fmaxf(nf.y + ef.y, 0.f);
            acc.z += fmaxf(nf.z + ef.z, 0.f);
            acc.w += fmaxf(nf.w + ef.w, 0.f);
        }
    }
    int rem = c - i0;
    if (rem > 0) {
        int2 p = (g < rem) ? pair[start + i0 + g] : make_int2(0, 0);
        for (int j = 0; j < rem; ++j) {
            int e = __shfl(p.x, gbase + j);
            int s = __shfl(p.y, gbase + j);
            f4 ef = __builtin_nontemporal_load(&efp[(size_t)e * 8 + g]);
            f4 nf = nfp[(size_t)s * 8 + g];
            acc.x += fmaxf(nf.x + ef.x, 0.f);
            acc.y += fmaxf(nf.y + ef.y, 0.f);
            acc.z += fmaxf(nf.z + ef.z, 0.f);
            acc.w += fmaxf(nf.w + ef.w, 0.f);
        }
    }

    float scale = 1.0f + eps[0];
    f4 h = nfp[(size_t)n * 8 + g];
    f4 o;
    o.x = scale * h.x + acc.x;
    o.y = scale * h.y + acc.y;
    o.z = scale * h.z + acc.z;
    o.w = scale * h.w + acc.w;
    ((f4*)out)[(size_t)n * 8 + g] = o;
}

// -------- fallback path (tiny ws): direct atomics --------

__global__ void fb_init_out(const float* __restrict__ node_feat,
                            const float* __restrict__ eps,
                            float* __restrict__ out) {
    int i = blockIdx.x * blockDim.x + threadIdx.x;
    const int n4 = N_NODES * D_FEAT / 4;
    float scale = 1.0f + eps[0];
    if (i < n4) {
        float4 v = ((const float4*)node_feat)[i];
        v.x *= scale; v.y *= scale; v.z *= scale; v.w *= scale;
        ((float4*)out)[i] = v;
    }
}

__global__ void fb_scatter(const float* __restrict__ node_feat,
                           const float* __restrict__ edge_feat,
                           const int* __restrict__ src,
                           const int* __restrict__ dst,
                           float* __restrict__ out) {
    int t = blockIdx.x * blockDim.x + threadIdx.x;
    int e = t >> 3;
    int g = t & 7;
    if (e >= N_EDGES) return;
    int s = src[e];
    int d = dst[e];
    float4 nf = ((const float4*)node_feat)[s * 8 + g];
    float4 ef = ((const float4*)edge_feat)[(size_t)e * 8 + g];
    float* op = out + (size_t)d * D_FEAT + g * 4;
    unsafeAtomicAdd(op + 0, fmaxf(nf.x + ef.x, 0.f));
    unsafeAtomicAdd(op + 1, fmaxf(nf.y + ef.y, 0.f));
    unsafeAtomicAdd(op + 2, fmaxf(nf.z + ef.z, 0.f));
    unsafeAtomicAdd(op + 3, fmaxf(nf.w + ef.w, 0.f));
}

extern "C" void kernel_launch(void* const* d_in, const int* in_sizes, int n_in,
                              void* d_out, int out_size, void* d_ws, size_t ws_size,
                              hipStream_t stream) {
    const float* node_feat = (const float*)d_in[0];
    const float* edge_feat = (const float*)d_in[1];
    const float* eps       = (const float*)d_in[2];
    const int*   src       = (const int*)d_in[3];
    const int*   dst       = (const int*)d_in[4];
    float* out = (float*)d_out;

    const int B = 256;
    const size_t need = ((size_t)WS_PAIR + 2ull * N_EDGES) * sizeof(int);

    if (ws_size < need) {
        // fallback: direct fp32 atomics (no ws)
        int n4 = N_NODES * D_FEAT / 4;
        fb_init_out<<<(n4 + B - 1) / B, B, 0, stream>>>(node_feat, eps, out);
        long long total = (long long)N_EDGES * 8;
        fb_scatter<<<(int)((total + B - 1) / B), B, 0, stream>>>(
            node_feat, edge_feat, src, dst, out);
        return;
    }

    int* ws = (int*)d_ws;
    int*  cnt   = ws + WS_CNT;
    int*  excl  = ws + WS_EXCL;
    int*  bsum  = ws + WS_BSUM;
    int*  bsumx = ws + WS_BSUMX;
    int*  rank  = ws + WS_RANK;
    int2* pair  = (int2*)(ws + WS_PAIR);

    hipMemsetAsync(cnt, 0, N_NODES * sizeof(int), stream);

    int nq = N_EDGES / 4;
    hist_rank<<<(nq + B - 1) / B, B, 0, stream>>>(dst, cnt, rank);
    scan_blocks<<<N_SCAN_BLOCKS, SCAN_BLOCK, 0, stream>>>(cnt, excl, bsum);
    scan_bsums<<<1, 64, 0, stream>>>(bsum, bsumx);

    scatter_pairs<<<(nq + B - 1) / B, B, 0, stream>>>(
        src, dst, excl, bsumx, rank, pair);

    long long ntotal = (long long)N_NODES * 8;
    reduce_gather<<<(int)((ntotal + B - 1) / B), B, 0, stream>>>(
        node_feat, edge_feat, eps, excl, bsumx, cnt, pair, out);
}